// Round 8
// baseline (220.678 us; speedup 1.0000x reference)
//
#include <hip/hip_runtime.h>

// RegLoss: l1(masked preds, targets) + 0.1 * mse(masked edge directions)
// preds, targets: [128, 1024, 151] fp32. Output: 1 fp32 scalar.
//
// Identities:
//   targets * (targets != 0) == targets       (masking targets is identity)
//   (m*pd - m*td)^2 == m*(pd - td)^2          (m in {0,1})
//   diff/(len+tiny) == (d2 > 0 ? diff*rsq(d2) : 0)  (~1e-7 rel; thresh 2.4e-2)
//   masked-parent of edge j == masked-child of edge j-1 in a chain (reg carry)
//
// R14: CHAIN-REUSE -- reduce scattered dwords, the one lever untested.
// Model that fits ALL rounds: scattered lane-dword serving ~2.4/cy/CU.
//   R6-R11 (LDS gather): 705 scattered dw/row -> 361K/CU / 152K cy = 2.4/cy
//   R12 (global gather): same dwords, 67us -- SAME rate through TA instead
//   of DS. Path/depth/occupancy/cache-residency all proven irrelevant.
// R13 failed its pre-commit (conflicts UP, 37MB spills) -- reverted.
//
// Mechanism: process each row's 47 edges as 8 chain-runs of 6 (lane =
// (row = lane&7, run = lane>>3)). In a chain, the parent operands (6 dw)
// are the previous step's child -- carried in registers, ALREADY MASKED.
// 30/47 edges become 9-dword tasks (child coords P,T + 3 masks); 17 full
// + 1 dummy stay 15. Scattered dwords/row: 705 -> 519 (x1.36). Metadata
// in a 48-entry __constant__ table, preloaded to 6 statically-indexed
// regs (rule #20). Staging = proven R9 reg-stage: linear layout, l1 from
// registers, no prefetch fight. 8-row chunks: 9.7KB/wave, 38.7KB/block,
// 4 blocks/CU, 16 waves/CU.
//
// Pre-committed: WRITE_SIZE ~130KB + VGPR 64-80 (no spills; else void).
// Model right => main 48-55us, VALUBusy 22-27%. Main still 62-65us =>
// model falsified => 63us plateau across 8 structures is the empirical
// serving-rate roofline; declare it next round.

#define N_ROWS   (128 * 1024)
#define ROW      151
#define N_EDGES  47
#define GRID     2048
#define BLOCK    256
#define CHUNKS   2
#define CHUNK_ROWS 8                   // 2048 blk * 4 waves * 2 * 8 = 131072
#define WAVE_DW  (CHUNK_ROWS * ROW)    // 1208 dwords per array per chunk
#define WAVE_F4  (WAVE_DW / 4)         // 302 float4 per array per chunk

#if __has_builtin(__builtin_amdgcn_rsqf)
__device__ __forceinline__ float fast_rsq(float x) { return __builtin_amdgcn_rsqf(x); }
#else
__device__ __forceinline__ float fast_rsq(float x) {
    float r; asm volatile("v_rsq_f32 %0, %1" : "=v"(r) : "v"(x)); return r;
}
#endif

// meta: bits[7:0]=3*parent, [15:8]=3*child, [21:16]=orig edge idx,
//       [22]=full (load parent), [23]=act
#define M_(p, c, e, f, a) ((unsigned)((p)*3) | ((unsigned)((c)*3) << 8) | \
                           ((unsigned)(e) << 16) | ((unsigned)(f) << 22) | \
                           ((unsigned)(a) << 23))
// 8 runs x 6 steps, step-major layout c_meta[j*8+g].
// Chains verified: every non-full entry's parent == previous entry's child.
__constant__ unsigned c_meta[48] = {
    // step j=0: run starts (all full)
    M_(0,1,0,1,1),   M_(31,32,33,1,1), M_(9,10,12,1,1),  M_(15,16,17,1,1),
    M_(21,22,21,1,1),M_(27,28,26,1,1), M_(38,39,38,1,1), M_(44,45,43,1,1),
    // step j=1
    M_(1,2,1,0,1),   M_(32,33,34,0,1), M_(10,11,13,0,1), M_(8,17,9,1,1),
    M_(22,23,22,0,1),M_(29,34,28,1,1), M_(39,40,39,0,1), M_(29,46,31,1,1),
    // step j=2
    M_(2,3,2,0,1),   M_(1,5,4,1,1),    M_(11,12,14,0,1), M_(17,18,18,0,1),
    M_(23,24,23,0,1),M_(34,35,35,0,1), M_(40,41,40,0,1), M_(46,47,44,0,1),
    // step j=3
    M_(3,29,3,0,1),  M_(5,6,5,0,1),    M_(8,13,8,1,1),   M_(18,19,19,0,1),
    M_(8,25,11,1,1), M_(35,36,36,0,1), M_(29,42,30,1,1), M_(47,48,45,0,1),
    // step j=4
    M_(29,30,27,0,1),M_(6,8,6,0,1),    M_(13,14,15,0,1), M_(19,20,20,0,1),
    M_(25,26,24,0,1),M_(36,37,37,0,1), M_(42,43,41,0,1), M_(48,49,46,0,1),
    // step j=5
    M_(30,31,32,0,1),M_(8,9,7,0,1),    M_(14,15,16,0,1), M_(8,21,10,1,1),
    M_(26,27,25,0,1),M_(29,38,29,1,1), M_(43,44,42,0,1), M_(48,49,46,0,0)};

__device__ __forceinline__ void acc_l1(float4 pv, float4 tv, float& l1) {
    float a0 = (tv.x != 0.f) ? pv.x : 0.f;
    float a1 = (tv.y != 0.f) ? pv.y : 0.f;
    float a2 = (tv.z != 0.f) ? pv.z : 0.f;
    float a3 = (tv.w != 0.f) ? pv.w : 0.f;
    l1 += fabsf(a0 - tv.x) + fabsf(a1 - tv.y)
        + fabsf(a2 - tv.z) + fabsf(a3 - tv.w);
}

__global__ __launch_bounds__(BLOCK, 4) void reg_loss_main(
        const float* __restrict__ preds, const float* __restrict__ targets,
        float* __restrict__ wsL, float* __restrict__ wsV) {
    // per-wave slab: [preds 1208][targets 1208] dw = 9664 B; x4 = 38.7 KB
    __shared__ float S[4][2 * WAVE_DW];
    __shared__ float redL[4], redV[4];

    const int t = threadIdx.x;
    const int lane = t & 63;
    const int wave = t >> 6;
    float* __restrict__ P = &S[wave][0];
    float* __restrict__ T = &S[wave][WAVE_DW];

    const int r = lane & 7;                // row within the 8-row chunk
    const int g = lane >> 3;               // chain-run 0..7

    // preload the run's 6 metadata words (static indexing after unroll)
    unsigned md[6];
#pragma unroll
    for (int j = 0; j < 6; ++j) md[j] = c_meta[j * 8 + g];

    const long long wid = (long long)blockIdx.x * 4 + wave;
    float l1 = 0.f, vel = 0.f;

#pragma unroll
    for (int c = 0; c < CHUNKS; ++c) {
        const float4* __restrict__ gp4 = reinterpret_cast<const float4*>(
            preds + (wid * CHUNKS + c) * WAVE_DW);
        const float4* __restrict__ gt4 = reinterpret_cast<const float4*>(
            targets + (wid * CHUNKS + c) * WAVE_DW);
        float4* __restrict__ P4 = reinterpret_cast<float4*>(P);
        float4* __restrict__ T4 = reinterpret_cast<float4*>(T);

        // ---- stage 8 rows (coalesced, linear) + l1 from registers ----
#pragma unroll
        for (int k = 0; k < 5; ++k) {
            int idx = lane + k * 64;
            if (k < 4 || lane < (WAVE_F4 - 256)) {   // 302: k=4 for lane<46
                float4 pv = gp4[idx];
                float4 tv = gt4[idx];
                P4[idx] = pv;
                T4[idx] = tv;
                acc_l1(pv, tv, l1);
            }
        }
        // same-wave DS ordering (wave-private slab): compiler's lgkmcnt
        // covers the write->read dependency; no barrier needed.

        const float* __restrict__ RP = P + r * ROW;
        const float* __restrict__ RT = T + r * ROW;

        // carried masked-child of the previous step (chain parent)
        float aCx = 0.f, aCy = 0.f, aCz = 0.f;
        float tCx = 0.f, tCy = 0.f, tCz = 0.f;

#pragma unroll
        for (int j = 0; j < 6; ++j) {
            unsigned m = md[j];
            int pOff = (int)(m & 0xffu);
            int cOff = (int)((m >> 8) & 0xffu);
            int eOff = (int)((m >> 16) & 0x3fu);
            bool full = (m >> 22) & 1u;
            float act = ((m >> 23) & 1u) ? 1.f : 0.f;

            // child coords (always read): 6 dwords
            float pcx = RP[cOff], pcy = RP[cOff + 1], pcz = RP[cOff + 2];
            float tcx = RT[cOff], tcy = RT[cOff + 1], tcz = RT[cOff + 2];
            // direction masks: 3 dwords
            float mg0 = RT[eOff], mg1 = RT[eOff + 47], mg2 = RT[eOff + 94];

            // parent: loaded+masked on full steps, else carried registers
            float apx, apy, apz, tpx, tpy, tpz;
            if (full) {
                float ppx = RP[pOff], ppy = RP[pOff + 1], ppz = RP[pOff + 2];
                tpx = RT[pOff]; tpy = RT[pOff + 1]; tpz = RT[pOff + 2];
                apx = (tpx != 0.f) ? ppx : 0.f;
                apy = (tpy != 0.f) ? ppy : 0.f;
                apz = (tpz != 0.f) ? ppz : 0.f;
            } else {
                apx = aCx; apy = aCy; apz = aCz;
                tpx = tCx; tpy = tCy; tpz = tCz;
            }

            // masked child
            float acx = (tcx != 0.f) ? pcx : 0.f;
            float acy = (tcy != 0.f) ? pcy : 0.f;
            float acz = (tcz != 0.f) ? pcz : 0.f;

            float pdx = apx - acx, pdy = apy - acy, pdz = apz - acz;
            float tdx = tpx - tcx, tdy = tpy - tcy, tdz = tpz - tcz;
            float pd2 = pdx * pdx + pdy * pdy + pdz * pdz;
            float td2 = tdx * tdx + tdy * tdy + tdz * tdz;
            float pinv = (pd2 > 0.f) ? fast_rsq(pd2) : 0.f;
            float tinv = (td2 > 0.f) ? fast_rsq(td2) : 0.f;
            float dx = pdx * pinv - tdx * tinv;
            float dy = pdy * pinv - tdy * tinv;
            float dz = pdz * pinv - tdz * tinv;
            float m0 = (mg0 != 0.f) ? act : 0.f;
            float m1 = (mg1 != 0.f) ? act : 0.f;
            float m2 = (mg2 != 0.f) ? act : 0.f;
            vel += m0 * dx * dx + m1 * dy * dy + m2 * dz * dz;

            // carry masked child -> next step's parent
            aCx = acx; aCy = acy; aCz = acz;
            tCx = tcx; tCy = tcy; tCz = tcz;
        }
    }

    // ---- block reduction -> per-block partials ----
#pragma unroll
    for (int off = 32; off > 0; off >>= 1) {
        l1  += __shfl_down(l1, off);
        vel += __shfl_down(vel, off);
    }
    if (lane == 0) { redL[wave] = l1; redV[wave] = vel; }
    __syncthreads();
    if (t == 0) {
        wsL[blockIdx.x] = redL[0] + redL[1] + redL[2] + redL[3];
        wsV[blockIdx.x] = redV[0] + redV[1] + redV[2] + redV[3];
    }
}

__global__ __launch_bounds__(BLOCK) void reg_loss_finalize(
        const float* __restrict__ wsL, const float* __restrict__ wsV,
        float* __restrict__ out) {
    __shared__ double rl[4], rv[4];
    const int t = threadIdx.x;
    const int lane = t & 63;
    const int wave = t >> 6;
    double L = 0.0, V = 0.0;
    for (int k = t; k < GRID; k += BLOCK) { L += wsL[k]; V += wsV[k]; }
#pragma unroll
    for (int off = 32; off > 0; off >>= 1) {
        L += __shfl_down(L, off);
        V += __shfl_down(V, off);
    }
    if (lane == 0) { rl[wave] = L; rv[wave] = V; }
    __syncthreads();
    if (t == 0) {
        double Ls = rl[0] + rl[1] + rl[2] + rl[3];
        double Vs = rv[0] + rv[1] + rv[2] + rv[3];
        out[0] = (float)(Ls / ((double)N_ROWS * 151.0)
                       + 0.1 * (Vs / ((double)N_ROWS * 141.0)));
    }
}

extern "C" void kernel_launch(void* const* d_in, const int* in_sizes, int n_in,
                              void* d_out, int out_size, void* d_ws, size_t ws_size,
                              hipStream_t stream) {
    const float* preds   = (const float*)d_in[0];
    const float* targets = (const float*)d_in[1];
    float* wsL = (float*)d_ws;
    float* wsV = wsL + GRID;
    float* out = (float*)d_out;

    reg_loss_main<<<GRID, BLOCK, 0, stream>>>(preds, targets, wsL, wsV);
    reg_loss_finalize<<<1, BLOCK, 0, stream>>>(wsL, wsV, out);
}

// Round 10
// 164.081 us; speedup vs baseline: 1.3449x; 1.3449x over previous
//
#include <hip/hip_runtime.h>

// RegLoss: l1(masked preds, targets) + 0.1 * mse(masked edge directions)
// preds, targets: [128, 1024, 151] fp32. Output: 1 fp32 scalar.
//
// Identities:
//   targets * (targets != 0) == targets       (masking targets is identity)
//   (m*pd - m*td)^2 == m*(pd - td)^2          (m in {0,1})
//   diff/(len+tiny) == (d2 > 0 ? diff*rsq(d2) : 0)  (~1e-7 rel; thresh 2.4e-2)
//
// R15b: NON-TEMPORAL streaming loads on the proven R9 structure.
// (R15a failed to compile: __builtin_nontemporal_load rejects
// HIP_vector_type; fixed with a native ext_vector_type(4) float. Same
// experiment, same pre-commits.)
//
// Post-audit of 9 rounds: the scattered-gather model only explains R12
// (global gather, TA-serialized); for the LDS rounds the gather accounts
// for ~25K cy/CU of the observed 152K => dead end (R13/R14 both voided on
// spills anyway). The ONE invariant across every clean 62-64us round:
// the 158MB streaming path always runs through L1 at ~4 B/cy/CU
// (2.5 TB/s), regardless of staging path (DMA vs reg), pipeline depth
// (0/1/2), occupancy (16 vs 32 w/CU), or data residency (L3-resident
// dispatches in R11 ran identical). That invariance = per-CU cap between
// CU and L2. Best-fit mechanism: L1 miss-tracking occupancy -- ~32
// outstanding line misses x 64B / ~500cy loaded latency ~= 4.1 B/cy/CU.
// Every round paid this toll; none bypassed it.
//
// Change (single variable vs R9): the 6 staging float4 loads become
// __builtin_nontemporal_load (MUBUF/global `nt` -- L1 bypass/evict-first).
// Touch-once stream => correct semantic too. Everything else identical
// to the 63.5us/VGPR-40/no-spill R9 baseline.
//
// Pre-committed: void-checks WRITE ~130KB, VGPR 40-64. Theory right =>
// main 30-45us, VALUBusy 30-40%, FETCH may rise toward 158MB. Null
// (62-65us clean) => the 4 B/cy/CU serving cap survives L1 bypass; all
// levers exhausted, one arithmetic fits all 10 structures => declare
// <<ROOFLINE>> next round.

#define N_ROWS   (128 * 1024)
#define ROW      151
#define N_EDGES  47
#define GRID     2048
#define BLOCK    256
#define CHUNKS   4                     // 2048 blk * 4 waves * 4 chunks * 4 rows
#define CHUNK_ROWS 4
#define CHUNK_DW (CHUNK_ROWS * ROW)    // 604 dwords per array per chunk
#define CHUNK_TASKS (CHUNK_ROWS * N_EDGES) // 188
#define BUF_DW (2 * CHUNK_DW)          // [preds 604][targets 604] = 4832 B

// native vector type accepted by __builtin_nontemporal_load (same 16B
// layout as float4)
typedef float f4 __attribute__((ext_vector_type(4)));

#if __has_builtin(__builtin_amdgcn_rsqf)
__device__ __forceinline__ float fast_rsq(float x) { return __builtin_amdgcn_rsqf(x); }
#else
__device__ __forceinline__ float fast_rsq(float x) {
    float r; asm volatile("v_rsq_f32 %0, %1" : "=v"(r) : "v"(x)); return r;
}
#endif

// Non-temporal 16B load: global_load_dwordx4 with nt policy (L1 bypass).
__device__ __forceinline__ f4 ldg4nt(const float* __restrict__ p) {
    return __builtin_nontemporal_load(reinterpret_cast<const f4*>(p));
}
__device__ __forceinline__ void st4(float* __restrict__ p, f4 v) {
    *reinterpret_cast<f4*>(p) = v;
}

// packed: low16 = parent*3 (dword offset in row), high16 = child*3
#define E(p, c) ((unsigned)((p) * 3) | ((unsigned)((c) * 3) << 16))
__constant__ unsigned c_edge[N_EDGES] = {
    E(0,1),  E(1,2),  E(2,3),  E(3,29), E(1,5),  E(5,6),  E(6,8),  E(8,9),
    E(8,13), E(8,17), E(8,21), E(8,25), E(9,10), E(10,11),E(11,12),E(13,14),
    E(14,15),E(15,16),E(17,18),E(18,19),E(19,20),E(21,22),E(22,23),E(23,24),
    E(25,26),E(26,27),E(27,28),E(29,30),E(29,34),E(29,38),E(29,42),E(29,46),
    E(30,31),E(31,32),E(32,33),E(34,35),E(35,36),E(36,37),E(38,39),E(39,40),
    E(40,41),E(42,43),E(43,44),E(44,45),E(46,47),E(47,48),E(48,49)};

// pre-summed LDS dword addresses: aP/aC = row_off + joint*3, aM = row_off + e
struct EdgeAddr { int aP[3], aC[3], aM[3]; };

__device__ __forceinline__ void acc_l1(f4 pv, f4 tv, float& l1) {
    float a0 = (tv.x != 0.f) ? pv.x : 0.f;
    float a1 = (tv.y != 0.f) ? pv.y : 0.f;
    float a2 = (tv.z != 0.f) ? pv.z : 0.f;
    float a3 = (tv.w != 0.f) ? pv.w : 0.f;
    l1 += fabsf(a0 - tv.x) + fabsf(a1 - tv.y)
        + fabsf(a2 - tv.z) + fabsf(a3 - tv.w);
}

// 188 edge tasks from LDS, mask applied at read time.
// k=0,1 fully active (tasks 0..127); k=2 active for lane<60 (tasks 128..187).
__device__ __forceinline__ void compute_edges(
        const float* __restrict__ B, const EdgeAddr& ea, int lane, float& vel) {
    const float* __restrict__ Bp = B;
    const float* __restrict__ Bt = B + CHUNK_DW;
#pragma unroll
    for (int k = 0; k < 3; ++k) {
        if (k < 2 || lane < (CHUNK_TASKS - 128)) {
            int aP = ea.aP[k], aC = ea.aC[k], aM = ea.aM[k];
            float tpx = Bt[aP], tpy = Bt[aP + 1], tpz = Bt[aP + 2];
            float tcx = Bt[aC], tcy = Bt[aC + 1], tcz = Bt[aC + 2];
            float ppx = Bp[aP], ppy = Bp[aP + 1], ppz = Bp[aP + 2];
            float pcx = Bp[aC], pcy = Bp[aC + 1], pcz = Bp[aC + 2];
            // masked preds
            float apx = (tpx != 0.f) ? ppx : 0.f;
            float apy = (tpy != 0.f) ? ppy : 0.f;
            float apz = (tpz != 0.f) ? ppz : 0.f;
            float acx = (tcx != 0.f) ? pcx : 0.f;
            float acy = (tcy != 0.f) ? pcy : 0.f;
            float acz = (tcz != 0.f) ? pcz : 0.f;
            float pdx = apx - acx, pdy = apy - acy, pdz = apz - acz;
            float tdx = tpx - tcx, tdy = tpy - tcy, tdz = tpz - tcz;
            float pd2 = pdx * pdx + pdy * pdy + pdz * pdz;
            float td2 = tdx * tdx + tdy * tdy + tdz * tdz;
            float pinv = (pd2 > 0.f) ? fast_rsq(pd2) : 0.f;
            float tinv = (td2 > 0.f) ? fast_rsq(td2) : 0.f;
            float dx = pdx * pinv - tdx * tinv;
            float dy = pdy * pinv - tdy * tinv;
            float dz = pdz * pinv - tdz * tinv;
            float m0 = (Bt[aM]      != 0.f) ? 1.f : 0.f;
            float m1 = (Bt[aM + 47] != 0.f) ? 1.f : 0.f;
            float m2 = (Bt[aM + 94] != 0.f) ? 1.f : 0.f;
            vel += m0 * dx * dx + m1 * dy * dy + m2 * dz * dz;
        }
    }
}

__global__ __launch_bounds__(BLOCK, 4) void reg_loss_main(
        const float* __restrict__ preds, const float* __restrict__ targets,
        float* __restrict__ wsL, float* __restrict__ wsV) {
    __shared__ float S[4][BUF_DW];         // 4 waves x 4832B = 19.3 KB/block
    __shared__ float redL[4], redV[4];

    const int t = threadIdx.x;
    const int lane = t & 63;
    const int wave = t >> 6;
    float* B = &S[wave][0];

    const long long wb =
        (long long)(blockIdx.x * 4 + wave) * (CHUNKS * CHUNK_DW);
    const float* gp = preds + wb;
    const float* gt = targets + wb;

    const int l4 = lane * 4;
    const bool tail = lane < 23;           // 23*16B = 368B tail (604-512 dw)
    const int off2 = tail ? (512 + l4) : l4;   // clamped: lanes >=23 re-read
                                               // lane-local bytes, masked at use

    // per-lane edge-task addresses (fixed across chunks): 9 VGPRs
    EdgeAddr ea;
#pragma unroll
    for (int k = 0; k < 3; ++k) {
        int task = lane + k * 64;
        bool a = task < CHUNK_TASKS;
        int r = a ? task / N_EDGES : 0;
        int e = a ? task - r * N_EDGES : 0;
        int roff = r * ROW;
        unsigned pk = c_edge[e];
        ea.aP[k] = roff + (int)(pk & 0xffff);
        ea.aC[k] = roff + (int)(pk >> 16);
        ea.aM[k] = roff + e;
    }

    float l1 = 0.f, vel = 0.f;
    f4 p0, p1, p2, t0, t1, t2;

    // prologue: issue chunk-0 loads (non-temporal: L1 bypass)
    p0 = ldg4nt(gp + l4);       p1 = ldg4nt(gp + 256 + l4);
    t0 = ldg4nt(gt + l4);       t1 = ldg4nt(gt + 256 + l4);
    p2 = ldg4nt(gp + off2);     t2 = ldg4nt(gt + off2);

#pragma unroll
    for (int c = 0; c < CHUNKS; ++c) {
        // stage chunk c to LDS (compiler inserts the vmcnt for reg arrival)
        st4(B + l4,                  p0);
        st4(B + 256 + l4,            p1);
        st4(B + CHUNK_DW + l4,       t0);
        st4(B + CHUNK_DW + 256 + l4, t1);
        if (tail) {
            st4(B + 512 + l4,            p2);
            st4(B + CHUNK_DW + 512 + l4, t2);
        }

        // l1 term directly from the staging registers (no LDS read)
        acc_l1(p0, t0, l1);
        acc_l1(p1, t1, l1);
        if (tail) acc_l1(p2, t2, l1);

        // issue chunk c+1 loads (non-temporal); latency hides under edges
        if (c + 1 < CHUNKS) {
            const float* cp = gp + (c + 1) * CHUNK_DW;
            const float* ct = gt + (c + 1) * CHUNK_DW;
            p0 = ldg4nt(cp + l4);       p1 = ldg4nt(cp + 256 + l4);
            t0 = ldg4nt(ct + l4);       t1 = ldg4nt(ct + 256 + l4);
            p2 = ldg4nt(cp + off2);     t2 = ldg4nt(ct + off2);
        }

        // edge gather from LDS (compiler inserts lgkmcnt for the ds RAW)
        compute_edges(B, ea, lane, vel);
    }

    // ---- block reduction -> per-block partials ----
#pragma unroll
    for (int off = 32; off > 0; off >>= 1) {
        l1  += __shfl_down(l1, off);
        vel += __shfl_down(vel, off);
    }
    if (lane == 0) { redL[wave] = l1; redV[wave] = vel; }
    __syncthreads();
    if (t == 0) {
        wsL[blockIdx.x] = redL[0] + redL[1] + redL[2] + redL[3];
        wsV[blockIdx.x] = redV[0] + redV[1] + redV[2] + redV[3];
    }
}

__global__ __launch_bounds__(BLOCK) void reg_loss_finalize(
        const float* __restrict__ wsL, const float* __restrict__ wsV,
        float* __restrict__ out) {
    __shared__ double rl[4], rv[4];
    const int t = threadIdx.x;
    const int lane = t & 63;
    const int wave = t >> 6;
    double L = 0.0, V = 0.0;
    for (int k = t; k < GRID; k += BLOCK) { L += wsL[k]; V += wsV[k]; }
#pragma unroll
    for (int off = 32; off > 0; off >>= 1) {
        L += __shfl_down(L, off);
        V += __shfl_down(V, off);
    }
    if (lane == 0) { rl[wave] = L; rv[wave] = V; }
    __syncthreads();
    if (t == 0) {
        double Ls = rl[0] + rl[1] + rl[2] + rl[3];
        double Vs = rv[0] + rv[1] + rv[2] + rv[3];
        out[0] = (float)(Ls / ((double)N_ROWS * 151.0)
                       + 0.1 * (Vs / ((double)N_ROWS * 141.0)));
    }
}

extern "C" void kernel_launch(void* const* d_in, const int* in_sizes, int n_in,
                              void* d_out, int out_size, void* d_ws, size_t ws_size,
                              hipStream_t stream) {
    const float* preds   = (const float*)d_in[0];
    const float* targets = (const float*)d_in[1];
    float* wsL = (float*)d_ws;
    float* wsV = wsL + GRID;
    float* out = (float*)d_out;

    reg_loss_main<<<GRID, BLOCK, 0, stream>>>(preds, targets, wsL, wsV);
    reg_loss_finalize<<<1, BLOCK, 0, stream>>>(wsL, wsV, out);
}